// Round 6
// baseline (449.888 us; speedup 1.0000x reference)
//
#include <hip/hip_runtime.h>
#include <hip/hip_bf16.h>

#define BB 4
#define SS 2048
#define DD 2048
#define HH 16
#define HDD 128

typedef __bf16 bf16x8_t __attribute__((ext_vector_type(8)));
typedef float f32x4 __attribute__((ext_vector_type(4)));
typedef float f32x16 __attribute__((ext_vector_type(16)));

static __device__ __forceinline__ unsigned short f2bf(float f) {
    union { float f; unsigned u; } v; v.f = f;
    unsigned r = v.u + 0x7fffu + ((v.u >> 16) & 1u);
    return (unsigned short)(r >> 16);
}

static __device__ __forceinline__ unsigned cvtpk_bf16(float lo, float hiv) {
    unsigned r;
    asm("v_cvt_pk_bf16_f32 %0, %1, %2" : "=v"(r) : "v"(lo), "v"(hiv));
    return r;
}

static __device__ __forceinline__ void pl32swap(unsigned& a, unsigned& b) {
    auto rr = __builtin_amdgcn_permlane32_swap((int)a, (int)b, false, false);
    a = (unsigned)rr[0];
    b = (unsigned)rr[1];
}

static __device__ __forceinline__ void gload_lds16(const void* g, void* lds) {
    __builtin_amdgcn_global_load_lds(
        (const __attribute__((address_space(1))) void*)g,
        (__attribute__((address_space(3))) void*)lds, 16, 0, 0);
}

// ---------------- convert x fp32 -> bf16 ----------------
__global__ void convert_x(const float* __restrict__ x, unsigned short* __restrict__ xb, int n) {
    int i = (blockIdx.x * blockDim.x + threadIdx.x) * 4;
    int stride = gridDim.x * blockDim.x * 4;
    for (; i < n; i += stride) {
        float4 v = *(const float4*)(x + i);
        ushort4 o;
        o.x = f2bf(v.x); o.y = f2bf(v.y); o.z = f2bf(v.z); o.w = f2bf(v.w);
        *(ushort4*)(xb + i) = o;
    }
}

// ---------------- transpose + convert weights: T[n][k] = W[k][n] ----------------
__global__ void transpose_w(const float* __restrict__ Wq, const float* __restrict__ Wk,
                            const float* __restrict__ Wv, const float* __restrict__ Wo,
                            unsigned short* __restrict__ WqkvT, unsigned short* __restrict__ WoT) {
    __shared__ float t[32][33];
    const int z = blockIdx.z;
    const float* W = (z == 0) ? Wq : (z == 1) ? Wk : (z == 2) ? Wv : Wo;
    unsigned short* T = (z < 3) ? (WqkvT + (size_t)z * DD * DD) : WoT;
    const int k0 = blockIdx.x * 32, n0 = blockIdx.y * 32;
    const int tx = threadIdx.x, ty = threadIdx.y;
#pragma unroll
    for (int i = 0; i < 4; ++i) {
        int r = ty + i * 8;
        t[r][tx] = W[(size_t)(k0 + r) * DD + n0 + tx];
    }
    __syncthreads();
#pragma unroll
    for (int i = 0; i < 4; ++i) {
        int r = ty + i * 8;
        T[(size_t)(n0 + r) * DD + k0 + tx] = f2bf(t[tx][r]);
    }
}

// ---------------- 256x256 GEMM, BK=64, 8 waves, m201-style per-phase interleave ----------------
// 4 phases per K-tile: (mq-half x k-half). Per phase: {dsr subtile; stage 1 half-tile;
// s_barrier; lgkmcnt(0); 16 MFMA (setprio); s_barrier}. Stage stream per tile t:
// p0: A(t+1).k1, p1: B(t+1).k1, p2: A(t+2).k0, p3: B(t+2).k0 (2 gloads each).
// vmcnt(8) at p1/p3 end only (4 half-tiles in flight). LDS: A [2slot][2kh][256][32]sh @0,
// B same @65536. Swizzle: 16B chunk c ^= (row&3), pre-applied on gload SOURCE, applied on dsr.
template <int MODE>
__global__ __launch_bounds__(512, 1) void gemm256(
    const unsigned short* __restrict__ A, const unsigned short* __restrict__ BT,
    unsigned short* __restrict__ outQ, unsigned short* __restrict__ outK,
    unsigned short* __restrict__ outV, float* __restrict__ outF,
    const float* __restrict__ bias) {
    __shared__ __attribute__((aligned(16))) char lds[131072];
    const int tid = threadIdx.x, l = tid & 63;
    const int w = tid >> 6;
    const int wr = w >> 2, wc = w & 3;
    const int nwg = gridDim.x * gridDim.y;
    int lin = blockIdx.y * gridDim.x + blockIdx.x;
    lin = (lin & 7) * (nwg >> 3) + (lin >> 3);
    const int m0 = (lin / gridDim.x) * 256;
    const int n0 = (lin % gridDim.x) * 256;

    f32x4 acc[8][4] = {};

    // staging: thread covers 16B chunk (row = tid>>2 [+128 for 2nd instr], chunk = tid&3)
    const int srow = tid >> 2;
    const int swz16 = ((tid & 3) ^ (srow & 3)) << 4;
    const char* aR = (const char*)A + ((size_t)(m0 + srow) * 2048) * 2 + swz16;
    const char* bR = (const char*)BT + ((size_t)(n0 + srow) * 2048) * 2 + swz16;
    const int dOff = tid * 16;

    auto stA = [&](int slot, int kt, int kh) {
        char* d = lds + slot * 32768 + kh * 16384 + dOff;
        const char* s = aR + kt * 128 + kh * 64;
        gload_lds16(s, d);
        gload_lds16(s + (size_t)128 * 4096, d + 8192);
    };
    auto stB = [&](int slot, int kt, int kh) {
        char* d = lds + 65536 + slot * 32768 + kh * 16384 + dOff;
        const char* s = bR + kt * 128 + kh * 64;
        gload_lds16(s, d);
        gload_lds16(s + (size_t)128 * 4096, d + 8192);
    };

    // prologue: A0k0 B0k0 A0k1 B0k1 A1k0 B1k0 (12 loads); loop in-flight target = 8
    stA(0, 0, 0); stB(0, 0, 0); stA(0, 0, 1); stB(0, 0, 1); stA(1, 1, 0); stB(1, 1, 0);
    asm volatile("s_waitcnt vmcnt(8)" ::: "memory");
    __builtin_amdgcn_s_barrier();

    const int lr = l & 15;
    const int rsw = (((l >> 4) ^ (lr & 3)) << 4);

    for (int t = 0; t < 32; ++t) {
        const int slot = t & 1;
        const char* As_ = lds + slot * 32768;
        const char* Bs_ = lds + 65536 + slot * 32768;
        const int tn1 = (t + 1 < 32) ? t + 1 : 31;
        const int tn2 = (t + 2 < 32) ? t + 2 : 31;
        const int sl1 = (t + 1) & 1;
        bf16x8_t aa[4], bb[4];

        // ---- p0: (mq0,k0) ----
#pragma unroll
        for (int ii = 0; ii < 4; ++ii) {
            int row = wr * 128 + ii * 16 + lr;
            aa[ii] = *(const bf16x8_t*)(As_ + row * 64 + rsw);
        }
#pragma unroll
        for (int nq = 0; nq < 4; ++nq) {
            int col = wc * 64 + nq * 16 + lr;
            bb[nq] = *(const bf16x8_t*)(Bs_ + col * 64 + rsw);
        }
        stA(sl1, tn1, 1);
        __builtin_amdgcn_s_barrier();
        asm volatile("s_waitcnt lgkmcnt(0)");
        __builtin_amdgcn_s_setprio(1);
#pragma unroll
        for (int ii = 0; ii < 4; ++ii)
#pragma unroll
            for (int nq = 0; nq < 4; ++nq)
                acc[ii][nq] = __builtin_amdgcn_mfma_f32_16x16x32_bf16(aa[ii], bb[nq], acc[ii][nq], 0, 0, 0);
        __builtin_amdgcn_s_setprio(0);
        __builtin_amdgcn_s_barrier();

        // ---- p1: (mq1,k0), bb reused ----
#pragma unroll
        for (int ii = 0; ii < 4; ++ii) {
            int row = wr * 128 + 64 + ii * 16 + lr;
            aa[ii] = *(const bf16x8_t*)(As_ + row * 64 + rsw);
        }
        stB(sl1, tn1, 1);
        __builtin_amdgcn_s_barrier();
        asm volatile("s_waitcnt lgkmcnt(0)");
        __builtin_amdgcn_s_setprio(1);
#pragma unroll
        for (int ii = 0; ii < 4; ++ii)
#pragma unroll
            for (int nq = 0; nq < 4; ++nq)
                acc[4 + ii][nq] = __builtin_amdgcn_mfma_f32_16x16x32_bf16(aa[ii], bb[nq], acc[4 + ii][nq], 0, 0, 0);
        __builtin_amdgcn_s_setprio(0);
        asm volatile("s_waitcnt vmcnt(8)" ::: "memory");
        __builtin_amdgcn_s_barrier();

        // ---- p2: (mq0,k1) ----
#pragma unroll
        for (int ii = 0; ii < 4; ++ii) {
            int row = wr * 128 + ii * 16 + lr;
            aa[ii] = *(const bf16x8_t*)(As_ + 16384 + row * 64 + rsw);
        }
#pragma unroll
        for (int nq = 0; nq < 4; ++nq) {
            int col = wc * 64 + nq * 16 + lr;
            bb[nq] = *(const bf16x8_t*)(Bs_ + 16384 + col * 64 + rsw);
        }
        stA(slot, tn2, 0);
        __builtin_amdgcn_s_barrier();
        asm volatile("s_waitcnt lgkmcnt(0)");
        __builtin_amdgcn_s_setprio(1);
#pragma unroll
        for (int ii = 0; ii < 4; ++ii)
#pragma unroll
            for (int nq = 0; nq < 4; ++nq)
                acc[ii][nq] = __builtin_amdgcn_mfma_f32_16x16x32_bf16(aa[ii], bb[nq], acc[ii][nq], 0, 0, 0);
        __builtin_amdgcn_s_setprio(0);
        __builtin_amdgcn_s_barrier();

        // ---- p3: (mq1,k1), bb reused ----
#pragma unroll
        for (int ii = 0; ii < 4; ++ii) {
            int row = wr * 128 + 64 + ii * 16 + lr;
            aa[ii] = *(const bf16x8_t*)(As_ + 16384 + row * 64 + rsw);
        }
        stB(slot, tn2, 0);
        __builtin_amdgcn_s_barrier();
        asm volatile("s_waitcnt lgkmcnt(0)");
        __builtin_amdgcn_s_setprio(1);
#pragma unroll
        for (int ii = 0; ii < 4; ++ii)
#pragma unroll
            for (int nq = 0; nq < 4; ++nq)
                acc[4 + ii][nq] = __builtin_amdgcn_mfma_f32_16x16x32_bf16(aa[ii], bb[nq], acc[4 + ii][nq], 0, 0, 0);
        __builtin_amdgcn_s_setprio(0);
        asm volatile("s_waitcnt vmcnt(8)" ::: "memory");
        __builtin_amdgcn_s_barrier();
    }

    // ---- epilogue ----
    const int hi4 = l >> 4;
    const int rbase = m0 + wr * 128 + (hi4 << 2);
    const int cbase = n0 + wc * 64 + lr;
    if (MODE == 0) {
#pragma unroll
        for (int nq = 0; nq < 4; ++nq) {
            int col = cbase + nq * 16;
            int mat = col >> 11;
            int nn = col & 2047;
            int h = nn >> 7, hd = nn & 127;
            if (mat == 2) {
#pragma unroll
                for (int i = 0; i < 8; ++i) {
                    int row = rbase + i * 16;
                    int b = row >> 11, s = row & 2047;
                    ushort4 pk;
                    pk.x = f2bf(acc[i][nq][0]); pk.y = f2bf(acc[i][nq][1]);
                    pk.z = f2bf(acc[i][nq][2]); pk.w = f2bf(acc[i][nq][3]);
                    *(ushort4*)(outV + ((size_t)(b * HH + h) * HDD + hd) * SS + s) = pk;
                }
            } else {
                unsigned short* outp = mat ? outK : outQ;
#pragma unroll
                for (int i = 0; i < 8; ++i) {
#pragma unroll
                    for (int r = 0; r < 4; ++r) {
                        int row = rbase + i * 16 + r;
                        int b = row >> 11, s = row & 2047;
                        outp[((size_t)(b * HH + h) * SS + s) * HDD + hd] = f2bf(acc[i][nq][r]);
                    }
                }
            }
        }
    } else {
#pragma unroll
        for (int nq = 0; nq < 4; ++nq) {
            int col = cbase + nq * 16;
            float bv = bias[col];
#pragma unroll
            for (int i = 0; i < 8; ++i) {
#pragma unroll
                for (int r = 0; r < 4; ++r) {
                    int row = rbase + i * 16 + r;
                    outF[(size_t)row * DD + col] = acc[i][nq][r] + bv;
                }
            }
        }
    }
}

// ---------------- flash attention: 4 warps x 32 q-rows, paired q-tiles for uniform blocks ----
__global__ __launch_bounds__(256, 2) void attn_kernel(
    const unsigned short* __restrict__ Q, const unsigned short* __restrict__ K,
    const unsigned short* __restrict__ VT, unsigned short* __restrict__ ctx) {
    __shared__ __attribute__((aligned(16))) unsigned short Ks[2][64 * 128];
    __shared__ __attribute__((aligned(16))) unsigned short Vs[2][128 * 64];
    __shared__ float Al[4][32];
    const int tid = threadIdx.x, w = tid >> 6, l = tid & 63;
    const int hi = l >> 5, l31 = l & 31;
    const int hb = hi * 16;
    const int swz = (l31 & 7) << 4;
    const int p = blockIdx.x, h = blockIdx.y, b = blockIdx.z;
    const int bh = b * HH + h;
    const float scale2 = 0.08838834764831845f * 1.4426950408889634f;

    const unsigned short* Qbh = Q + (size_t)bh * SS * HDD;
    const char* Kbh = (const char*)(K + (size_t)bh * SS * HDD);
    const char* Vbh = (const char*)(VT + (size_t)bh * HDD * SS);

    const char* kbase[4];
    const char* vbase[4];
#pragma unroll
    for (int i = 0; i < 4; ++i) {
        int cp = (i * 256 + tid) * 16;
        int krow = cp >> 8, kcb = cp & 255;
        kbase[i] = Kbh + (size_t)krow * 256 + (kcb ^ ((krow & 7) << 4));
        int vrow = cp >> 7, vcb = cp & 127;
        vbase[i] = Vbh + (size_t)vrow * (SS * 2) + (vcb ^ ((vrow & 7) << 4));
    }

    auto stage = [&](int buf, int kv0) {
#pragma unroll
        for (int i = 0; i < 4; ++i) {
            int cp = (i * 256 + tid) * 16;
            gload_lds16(kbase[i] + (size_t)kv0 * 256, (char*)&Ks[buf][0] + cp);
            gload_lds16(vbase[i] + (size_t)kv0 * 2, (char*)&Vs[buf][0] + cp);
        }
    };

    for (int pass = 0; pass < 2; ++pass) {
        const int qt = pass ? p : 15 - p;
        const int q0w = qt * 128 + w * 32;
        const int qabs = q0w + l31;
        const int nkv = 2 * qt + 2;

        bf16x8_t qf[8];
#pragma unroll
        for (int ds = 0; ds < 8; ++ds)
            qf[ds] = *(const bf16x8_t*)(Qbh + (size_t)qabs * HDD + ds * 16 + hi * 8);

        float m_r = -1e30f, l_r = 0.f;
        f32x16 o0 = {}, o1 = {}, o2 = {}, o3 = {};

        int buf = 0;
        stage(0, 0);
        __syncthreads();

        for (int kt = 0; kt < nkv; ++kt) {
            const int kv0 = kt * 64;
            if (kt + 1 < nkv) stage(buf ^ 1, kv0 + 64);

            if (kv0 <= q0w + 31) {
                const char* Kb = (const char*)&Ks[buf][0];
                const char* Vb = (const char*)&Vs[buf][0];
                f32x16 s0 = {}, s1 = {};
                {
                    bf16x8_t kf[8];
                    const int rb = l31 * 256;
#pragma unroll
                    for (int ds = 0; ds < 8; ++ds)
                        kf[ds] = *(const bf16x8_t*)(Kb + rb + ((ds * 32 + hb) ^ swz));
                    __builtin_amdgcn_s_setprio(1);
#pragma unroll
                    for (int ds = 0; ds < 8; ++ds)
                        s0 = __builtin_amdgcn_mfma_f32_32x32x16_bf16(kf[ds], qf[ds], s0, 0, 0, 0);
                    __builtin_amdgcn_s_setprio(0);
#pragma unroll
                    for (int ds = 0; ds < 8; ++ds)
                        kf[ds] = *(const bf16x8_t*)(Kb + rb + 32 * 256 + ((ds * 32 + hb) ^ swz));
                    __builtin_amdgcn_s_setprio(1);
#pragma unroll
                    for (int ds = 0; ds < 8; ++ds)
                        s1 = __builtin_amdgcn_mfma_f32_32x32x16_bf16(kf[ds], qf[ds], s1, 0, 0, 0);
                    __builtin_amdgcn_s_setprio(0);
                }

                if (kv0 + 63 > q0w) {
                    const int qrel = qabs - kv0;
#pragma unroll
                    for (int r = 0; r < 16; ++r) {
                        const int kl = (r & 3) + 8 * (r >> 2) + 4 * hi;
                        s0[r] = (kl > qrel) ? -1e30f : s0[r] * scale2;
                        s1[r] = (kl + 32 > qrel) ? -1e30f : s1[r] * scale2;
                    }
                } else {
#pragma unroll
                    for (int r = 0; r < 16; ++r) { s0[r] *= scale2; s1[r] *= scale2; }
                }

                float mx = s0[0];
#pragma unroll
                for (int r = 1; r < 16; ++r) mx = fmaxf(mx, s0[r]);
#pragma unroll
                for (int r = 0; r < 16; ++r) mx = fmaxf(mx, s1[r]);
                {
                    unsigned mu = __float_as_uint(mx), mu2 = mu;
                    pl32swap(mu, mu2);
                    mx = fmaxf(__uint_as_float(mu), __uint_as_float(mu2));
                }

                if (__any(mx - m_r > 8.f)) {
                    float mnew = fmaxf(m_r, mx);
                    float alpha = exp2f(m_r - mnew);
                    m_r = mnew;
                    l_r *= alpha;
                    Al[w][l31] = alpha;
#pragma unroll
                    for (int r = 0; r < 16; ++r) {
                        float ar = Al[w][(r & 3) + 8 * (r >> 2) + 4 * hi];
                        o0[r] *= ar; o1[r] *= ar; o2[r] *= ar; o3[r] *= ar;
                    }
                }

                float ps = 0.f;
#pragma unroll
                for (int r = 0; r < 16; ++r) { s0[r] = exp2f(s0[r] - m_r); ps += s0[r]; }
#pragma unroll
                for (int r = 0; r < 16; ++r) { s1[r] = exp2f(s1[r] - m_r); ps += s1[r]; }
                {
                    unsigned pu = __float_as_uint(ps), pu2 = pu;
                    pl32swap(pu, pu2);
                    l_r += __uint_as_float(pu) + __uint_as_float(pu2);
                }

                bf16x8_t pa[4];
                {
                    union { unsigned u[4]; bf16x8_t v; } uu;
#define MK_PA(SV, BASE, OUT)                                     \
                    {                                            \
                        unsigned X0 = cvtpk_bf16(SV[BASE + 0], SV[BASE + 1]); \
                        unsigned Y0 = cvtpk_bf16(SV[BASE + 4], SV[BASE + 5]); \
                        pl32swap(X0, Y0);                        \
                        unsigned X1 = cvtpk_bf16(SV[BASE + 2], SV[BASE + 3]); \
                        unsigned Y1 = cvtpk_bf16(SV[BASE + 6], SV[BASE + 7]); \
                        pl32swap(X1, Y1);                        \
                        uu.u[0] = X0; uu.u[1] = X1; uu.u[2] = Y0; uu.u[3] = Y1; \
                        OUT = uu.v;                              \
                    }
                    MK_PA(s0, 0, pa[0]);
                    MK_PA(s0, 8, pa[1]);
                    MK_PA(s1, 0, pa[2]);
                    MK_PA(s1, 8, pa[3]);
#undef MK_PA
                }

#pragma unroll
                for (int ks = 0; ks < 4; ++ks) {
                    bf16x8_t vf[4];
#pragma unroll
                    for (int dsub = 0; dsub < 4; ++dsub)
                        vf[dsub] = *(const bf16x8_t*)(Vb + (dsub * 32 + l31) * 128 + ((ks * 32 + hb) ^ swz));
                    __builtin_amdgcn_s_setprio(1);
                    o0 = __builtin_amdgcn_mfma_f32_32x32x16_bf16(pa[ks], vf[0], o0, 0, 0, 0);
                    o1 = __builtin_amdgcn_mfma_f32_32x32x16_bf16(pa[ks], vf[1], o1, 0, 0, 0);
                    o2 = __builtin_amdgcn_mfma_f32_32x32x16_bf16(pa[ks], vf[2], o2, 0, 0, 0);
                    o3 = __builtin_amdgcn_mfma_f32_32x32x16_bf16(pa[ks], vf[3], o3, 0, 0, 0);
                    __builtin_amdgcn_s_setprio(0);
                }
            }
            __syncthreads();
            buf ^= 1;
        }

        Al[w][l31] = 1.f / l_r;
        unsigned short* cb_ = ctx + (size_t)b * SS * DD + (size_t)h * HDD;
#pragma unroll
        for (int r = 0; r < 16; ++r) {
            const int ql = (r & 3) + 8 * (r >> 2) + 4 * hi;
            float inv = Al[w][ql];
            const size_t rowoff = (size_t)(q0w + ql) * DD;
            cb_[rowoff + 0 * 32 + l31] = f2bf(o0[r] * inv);
            cb_[rowoff + 1 * 32 + l31] = f2bf(o1[r] * inv);
            cb_[rowoff + 2 * 32 + l31] = f2bf(o2[r] * inv);
            cb_[rowoff + 3 * 32 + l31] = f2bf(o3[r] * inv);
        }
    }
}

extern "C" void kernel_launch(void* const* d_in, const int* in_sizes, int n_in,
                              void* d_out, int out_size, void* d_ws, size_t ws_size,
                              hipStream_t stream) {
    (void)in_sizes; (void)n_in; (void)out_size; (void)ws_size;
    const float* x  = (const float*)d_in[0];
    const float* Wq = (const float*)d_in[1];
    const float* Wk = (const float*)d_in[2];
    const float* Wv = (const float*)d_in[3];
    const float* Wo = (const float*)d_in[4];
    const float* bo = (const float*)d_in[5];

    char* ws = (char*)d_ws;
    unsigned short* xb    = (unsigned short*)(ws);
    unsigned short* WqkvT = (unsigned short*)(ws + (32u << 20));
    unsigned short* WoT   = (unsigned short*)(ws + (56u << 20));
    unsigned short* Qb    = (unsigned short*)(ws + (64u << 20));
    unsigned short* Kb    = (unsigned short*)(ws + (96u << 20));
    unsigned short* VTb   = (unsigned short*)(ws + (160u << 20));
    unsigned short* ctx   = xb;  // xb dead after QKV GEMM

    convert_x<<<4096, 256, 0, stream>>>(x, xb, BB * SS * DD);
    transpose_w<<<dim3(64, 64, 4), dim3(32, 8), 0, stream>>>(Wq, Wk, Wv, Wo, WqkvT, WoT);
    gemm256<0><<<dim3(24, 32), 512, 0, stream>>>(xb, WqkvT, Qb, Kb, VTb, nullptr, nullptr);
    attn_kernel<<<dim3(8, HH, BB), 256, 0, stream>>>(Qb, Kb, VTb, ctx);
    gemm256<1><<<dim3(8, 32), 512, 0, stream>>>(ctx, WoT, nullptr, nullptr, nullptr, (float*)d_out, bo);
}